// Round 7
// baseline (186.913 us; speedup 1.0000x reference)
//
#include <hip/hip_runtime.h>

#define BB 32
#define CC 512
#define COO 512
#define HH 56
#define WW 56
#define HW 3136
#define NPOS 100352      // B*H*W
#define EPSF 1e-5f

typedef unsigned long long u64;
typedef unsigned int u32;
typedef unsigned short u16;

// ---------------- workspace layout (bytes) ----------------  total 6,460,928
// s1     : u64[8][NPOS]  = 6,422,528   stage-1 sign bits (word-major)
// wbits  : u64[512*8]    = 32,768      pointwise weight sign bits
// wn     : u64[9*8]      = 576         ~sign(w_dw) per tap per cw
// NT     : u64[3*8*5]    = 960         per-(Nv cat, cw): 4 planes of ~T* + flip
// bn2inv/bn2beta : float[512] each
#define OFF_S1      0
#define OFF_WBITS   6422528
#define OFF_WN      6455296
#define OFF_NT      6455872
#define OFF_BN2INV  6456832
#define OFF_BN2BETA 6458880

__global__ __launch_bounds__(256) void setup_kernel(
    const float* __restrict__ w_dw, const float* __restrict__ w_pw,
    const float* __restrict__ g1, const float* __restrict__ b1,
    const float* __restrict__ m1, const float* __restrict__ v1,
    const float* __restrict__ g2, const float* __restrict__ b2,
    const float* __restrict__ m2, const float* __restrict__ v2,
    u64* __restrict__ wbits, u64* __restrict__ wn, u64* __restrict__ NT,
    float* __restrict__ bn2inv, float* __restrict__ bn2beta) {
    const int t = blockIdx.x * 256 + threadIdx.x;   // 0..4095

    // pointwise weight sign bits (all 4096 threads)
    {
        int o = t >> 3, wi = t & 7;
        const float* wp = w_pw + (size_t)o * CC + wi * 64;
        u64 wrd = 0;
        #pragma unroll 8
        for (int k = 0; k < 64; ++k)
            wrd |= (u64)(wp[k] >= 0.f) << k;
        wbits[t] = wrd;
    }

    if (t < CC) {                       // BN2 affine
        float i2 = g2[t] / sqrtf(v2[t] + EPSF);
        bn2inv[t]  = i2;
        bn2beta[t] = b2[t] - m2[t] * i2;
    } else if (t >= 512 && t < 584) {   // depthwise weight ~sign words
        int q = t - 512, cw = q & 7, tap = q >> 3;   // tap = kh*3+kw
        u64 wv = 0;
        for (int cl = 0; cl < 64; ++cl)
            wv |= (u64)(w_dw[(size_t)(cw * 64 + cl) * 9 + tap] < 0.f) << cl;
        wn[tap * 8 + cw] = wv;
    } else if (t >= 1024 && t < 1048) { // BN1 threshold bitplanes
        int q = t - 1024, cat = q / 8, cw = q % 8;
        const int Nv = (cat == 0) ? 9 : ((cat == 1) ? 6 : 4);
        u64 p0 = 0, p1 = 0, p2 = 0, p3 = 0, F = 0;
        for (int cl = 0; cl < 64; ++cl) {
            int c = cw * 64 + cl;
            float i1 = g1[c] / sqrtf(v1[c] + EPSF);
            float be = b1[c] - m1[c] * i1;
            int T, f;
            if (i1 > 0.f) {
                double h = ((double)Nv - (double)be / (double)i1) * 0.5;
                f = 0;
                if (!(h > 0.0)) T = 0;
                else if (h > 15.0) T = 15;
                else T = (int)ceil(h);
            } else if (i1 < 0.f) {
                double h = ((double)Nv - (double)be / (double)i1) * 0.5;
                f = 1;
                if (h < 0.0) T = 0;
                else if (h >= 15.0) T = 15;
                else { T = (int)floor(h) + 1; if (T > 15) T = 15; }
            } else {
                f = 0;
                T = (be >= 0.f) ? 0 : 15;   // always true / never true (E<=9<15)
            }
            unsigned nt = (~(unsigned)T) & 0xFu;
            p0 |= (u64)(nt & 1) << cl;
            p1 |= (u64)((nt >> 1) & 1) << cl;
            p2 |= (u64)((nt >> 2) & 1) << cl;
            p3 |= (u64)((nt >> 3) & 1) << cl;
            F  |= (u64)f << cl;
        }
        u64* d = NT + (size_t)(cat * 8 + cw) * 5;
        d[0] = p0; d[1] = p1; d[2] = p2; d[3] = p3; d[4] = F;
    }
}

__device__ __forceinline__ void fa(u64 a, u64 b, u64 c, u64& s, u64& cy) {
    u64 ab = a ^ b;
    s  = ab ^ c;
    cy = (ab & c) | (a & b);
}

// Fused: contiguous-read binarize -> ballot -> LDS 64x64 bit-transpose ->
// depthwise 3x3 + BN1 + sign (bit-domain) -> s1
// grid (strip=4, cw=8, b=32) x 512; strip covers 14 output rows (16 staged rows)
__global__ __launch_bounds__(512) void dwfused_kernel(
    const float* __restrict__ x, const u64* __restrict__ wn,
    const u64* __restrict__ NT, u64* __restrict__ s1) {
    __shared__ u64 cm[64 * 14];          // channel-major: cm[c][w], 7168 B
    __shared__ u64 xb[16 * 56];          // position-major: rows r0-1..r0+14, 7168 B
    const int strip = blockIdx.x;
    const int cw    = blockIdx.y;
    const int b     = blockIdx.z;
    const int tid   = threadIdx.x;
    const int wid   = tid >> 6;          // 0..7
    const int lane  = tid & 63;
    const int r0    = strip * 14;
    const int p0    = (r0 - 1) * WW;     // may be -56

    const float* xbase = x + ((size_t)b * CC + cw * 64) * HW;

    // ---- Phase A: contiguous loads + ballot -> cm[c][w]
    // task = c*14 + w ; one wave-instruction reads 256B contiguous of plane c
    for (int task = wid; task < 896; task += 8) {
        const int c = task / 14;
        const int w = task - c * 14;
        int pos = p0 + w * 64 + lane;
        pos = (pos < 0) ? 0 : ((pos > HW - 1) ? HW - 1 : pos);   // clamp (garbage rows masked later)
        const float v = xbase[c * HW + pos];
        const u64 bal = __ballot((__float_as_uint(v) >> 31) == 0u);  // bit=1 <=> x>=0
        if (lane == 0) cm[task] = bal;
    }
    __syncthreads();

    // ---- Phase B: 64x64 bit-transpose via broadcast reads -> xb[pos]
    // group g covers strip-local positions 64g..64g+63; lane q builds word for pos 64g+q
    for (int g = wid; g < 14; g += 8) {
        const u64* cmg = cm + g;
        u64 acc = 0;
        #pragma unroll
        for (int c = 0; c < 64; ++c) {
            u64 wv = cmg[c * 14];                 // same addr for all lanes -> broadcast
            acc |= ((wv >> lane) & 1ull) << c;
        }
        xb[g * 64 + lane] = acc;
    }
    __syncthreads();

    // ---- Phase C: 784 word-tasks (14 rows x 56 cols) over 512 threads (verified logic)
    const u64 w00 = wn[0*8+cw], w01 = wn[1*8+cw], w02 = wn[2*8+cw];
    const u64 w10 = wn[3*8+cw], w11 = wn[4*8+cw], w12 = wn[5*8+cw];
    const u64 w20 = wn[6*8+cw], w21 = wn[7*8+cw], w22 = wn[8*8+cw];

    for (int task = tid; task < 784; task += 512) {
        const int q = task / 56;
        const int c = task - q * 56;
        const int r = r0 + q;
        const int lrow = q + 1;
        const int cm_ = (c == 0)  ? 0  : c - 1;
        const int cp_ = (c == 55) ? 55 : c + 1;

        const u64* rT = xb + (lrow - 1) * 56;
        const u64* rM = xb + lrow * 56;
        const u64* rB = xb + (lrow + 1) * 56;
        u64 t0 = rT[cm_], t1 = rT[c], t2 = rT[cp_];
        u64 m0 = rM[cm_], m1 = rM[c], m2 = rM[cp_];
        u64 b0 = rB[cm_], b1 = rB[c], b2 = rB[cp_];

        const u64 mt = (r > 0)  ? ~0ull : 0ull;
        const u64 mb = (r < 55) ? ~0ull : 0ull;
        const u64 ml = (c > 0)  ? ~0ull : 0ull;
        const u64 mr = (c < 55) ? ~0ull : 0ull;

        u64 e0 = (t0 ^ w00) & mt & ml;
        u64 e1 = (t1 ^ w01) & mt;
        u64 e2 = (t2 ^ w02) & mt & mr;
        u64 e3 = (m0 ^ w10) & ml;
        u64 e4 = (m1 ^ w11);
        u64 e5 = (m2 ^ w12) & mr;
        u64 e6 = (b0 ^ w20) & mb & ml;
        u64 e7 = (b1 ^ w21) & mb;
        u64 e8 = (b2 ^ w22) & mb & mr;

        u64 sa, ca, sb, cb, sc, cc, E0, cd, se, ce;
        fa(e0, e1, e2, sa, ca);
        fa(e3, e4, e5, sb, cb);
        fa(e6, e7, e8, sc, cc);
        fa(sa, sb, sc, E0, cd);
        fa(ca, cb, cc, se, ce);
        u64 E1 = se ^ cd, cf = se & cd;
        u64 E2 = ce ^ cf, E3 = ce & cf;

        const int rowe = (r == 0) | (r == 55);
        const int cole = (c == 0) | (c == 55);
        const u64* NTp = NT + (size_t)(rowe + cole) * 40 + (size_t)cw * 5;
        u64 n0 = NTp[0], n1 = NTp[1], n2 = NTp[2], n3 = NTp[3], Fv = NTp[4];

        // carry-out of E + ~T* + 1  ->  (E >= T*)
        u64 cr = E0 | n0;
        cr = (E1 & n1) | (cr & (E1 | n1));
        cr = (E2 & n2) | (cr & (E2 | n2));
        cr = (E3 & n3) | (cr & (E3 | n3));

        s1[(size_t)cw * NPOS + (size_t)b * HW + r * WW + c] = cr ^ Fv;
    }
}

// K2: 1x1 binary conv via XNOR-popcount + BN2 (no LDS; weights via scalar cache)
__global__ __launch_bounds__(256) void pw_kernel(
    const u64* __restrict__ s1, const u64* __restrict__ wbits,
    const float* __restrict__ bn2inv, const float* __restrict__ bn2beta,
    float* __restrict__ out) {
    const int tid = threadIdx.x;
    const int o0  = blockIdx.y * 128;

    const size_t p   = (size_t)blockIdx.x * 256 + tid;
    const int    b   = (int)(p / HW);
    const int    idx = (int)(p - (size_t)b * HW);

    u64 r0 = s1[0u * NPOS + p], r1 = s1[1u * NPOS + p];
    u64 r2 = s1[2u * NPOS + p], r3 = s1[3u * NPOS + p];
    u64 r4 = s1[4u * NPOS + p], r5 = s1[5u * NPOS + p];
    u64 r6 = s1[6u * NPOS + p], r7 = s1[7u * NPOS + p];

    const u64*   wp  = wbits + (size_t)o0 * 8;     // wave-uniform -> s_load
    const float* ivp = bn2inv + o0;
    const float* btp = bn2beta + o0;
    float* outp = out + ((size_t)b * COO + o0) * HW + idx;

    #pragma unroll 4
    for (int ol = 0; ol < 128; ++ol) {
        const u64* w8 = wp + ol * 8;
        int d = __popcll(r0 ^ w8[0]) + __popcll(r1 ^ w8[1])
              + __popcll(r2 ^ w8[2]) + __popcll(r3 ^ w8[3])
              + __popcll(r4 ^ w8[4]) + __popcll(r5 ^ w8[5])
              + __popcll(r6 ^ w8[6]) + __popcll(r7 ^ w8[7]);
        float res = (float)(CC - 2 * d);
        outp[(size_t)ol * HW] = fmaf(res, ivp[ol], btp[ol]);
    }
}

extern "C" void kernel_launch(void* const* d_in, const int* in_sizes, int n_in,
                              void* d_out, int out_size, void* d_ws, size_t ws_size,
                              hipStream_t stream) {
    const float* x    = (const float*)d_in[0];
    const float* w_dw = (const float*)d_in[1];
    const float* w_pw = (const float*)d_in[2];
    const float* g1   = (const float*)d_in[3];
    const float* b1   = (const float*)d_in[4];
    const float* m1   = (const float*)d_in[5];
    const float* v1   = (const float*)d_in[6];
    const float* g2   = (const float*)d_in[7];
    const float* b2   = (const float*)d_in[8];
    const float* m2   = (const float*)d_in[9];
    const float* v2   = (const float*)d_in[10];

    char* ws = (char*)d_ws;
    u64*   s1      = (u64*)(ws + OFF_S1);
    u64*   wbits   = (u64*)(ws + OFF_WBITS);
    u64*   wn      = (u64*)(ws + OFF_WN);
    u64*   NTarr   = (u64*)(ws + OFF_NT);
    float* bn2inv  = (float*)(ws + OFF_BN2INV);
    float* bn2beta = (float*)(ws + OFF_BN2BETA);

    setup_kernel<<<16, 256, 0, stream>>>(w_dw, w_pw, g1, b1, m1, v1, g2, b2, m2, v2,
                                         wbits, wn, NTarr, bn2inv, bn2beta);

    dim3 gf(4, 8, BB);
    dwfused_kernel<<<gf, 512, 0, stream>>>(x, wn, NTarr, s1);

    dim3 g2d(392, 4);
    pw_kernel<<<g2d, 256, 0, stream>>>(s1, wbits, bn2inv, bn2beta, (float*)d_out);
}

// Round 8
// 164.341 us; speedup vs baseline: 1.1374x; 1.1374x over previous
//
#include <hip/hip_runtime.h>

#define BB 32
#define CC 512
#define COO 512
#define HH 56
#define WW 56
#define HW 3136
#define NPOS 100352      // B*H*W
#define EPSF 1e-5f

typedef unsigned long long u64;
typedef unsigned int u32;
typedef unsigned short u16;

// ---------------- workspace layout (bytes) ----------------  total 6,460,928
// s1     : u64[8][NPOS]  = 6,422,528   stage-1 sign bits (word-major)
// wbits  : u64[512*8]    = 32,768      pointwise weight sign bits
// wn     : u64[9*8]      = 576         ~sign(w_dw) per tap per cw
// NT     : u64[3*8*5]    = 960         per-(Nv cat, cw): 4 planes of ~T* + flip
// bn2inv/bn2beta : float[512] each
// xbits  : u64[8][NPOS]  lives in d_out scratch (overwritten by pw at the end)
#define OFF_S1      0
#define OFF_WBITS   6422528
#define OFF_WN      6455296
#define OFF_NT      6455872
#define OFF_BN2INV  6456832
#define OFF_BN2BETA 6458880

__global__ __launch_bounds__(256) void setup_kernel(
    const float* __restrict__ w_dw, const float* __restrict__ w_pw,
    const float* __restrict__ g1, const float* __restrict__ b1,
    const float* __restrict__ m1, const float* __restrict__ v1,
    const float* __restrict__ g2, const float* __restrict__ b2,
    const float* __restrict__ m2, const float* __restrict__ v2,
    u64* __restrict__ wbits, u64* __restrict__ wn, u64* __restrict__ NT,
    float* __restrict__ bn2inv, float* __restrict__ bn2beta) {
    const int t = blockIdx.x * 256 + threadIdx.x;   // 0..4095

    // pointwise weight sign bits (all 4096 threads)
    {
        int o = t >> 3, wi = t & 7;
        const float* wp = w_pw + (size_t)o * CC + wi * 64;
        u64 wrd = 0;
        #pragma unroll 8
        for (int k = 0; k < 64; ++k)
            wrd |= (u64)(wp[k] >= 0.f) << k;
        wbits[t] = wrd;
    }

    if (t < CC) {                       // BN2 affine
        float i2 = g2[t] / sqrtf(v2[t] + EPSF);
        bn2inv[t]  = i2;
        bn2beta[t] = b2[t] - m2[t] * i2;
    } else if (t >= 512 && t < 584) {   // depthwise weight ~sign words
        int q = t - 512, cw = q & 7, tap = q >> 3;   // tap = kh*3+kw
        u64 wv = 0;
        for (int cl = 0; cl < 64; ++cl)
            wv |= (u64)(w_dw[(size_t)(cw * 64 + cl) * 9 + tap] < 0.f) << cl;
        wn[tap * 8 + cw] = wv;
    } else if (t >= 1024 && t < 1048) { // BN1 threshold bitplanes
        int q = t - 1024, cat = q / 8, cw = q % 8;
        const int Nv = (cat == 0) ? 9 : ((cat == 1) ? 6 : 4);
        u64 p0 = 0, p1 = 0, p2 = 0, p3 = 0, F = 0;
        for (int cl = 0; cl < 64; ++cl) {
            int c = cw * 64 + cl;
            float i1 = g1[c] / sqrtf(v1[c] + EPSF);
            float be = b1[c] - m1[c] * i1;
            int T, f;
            if (i1 > 0.f) {
                double h = ((double)Nv - (double)be / (double)i1) * 0.5;
                f = 0;
                if (!(h > 0.0)) T = 0;
                else if (h > 15.0) T = 15;
                else T = (int)ceil(h);
            } else if (i1 < 0.f) {
                double h = ((double)Nv - (double)be / (double)i1) * 0.5;
                f = 1;
                if (h < 0.0) T = 0;
                else if (h >= 15.0) T = 15;
                else { T = (int)floor(h) + 1; if (T > 15) T = 15; }
            } else {
                f = 0;
                T = (be >= 0.f) ? 0 : 15;   // always true / never true (E<=9<15)
            }
            unsigned nt = (~(unsigned)T) & 0xFu;
            p0 |= (u64)(nt & 1) << cl;
            p1 |= (u64)((nt >> 1) & 1) << cl;
            p2 |= (u64)((nt >> 2) & 1) << cl;
            p3 |= (u64)((nt >> 3) & 1) << cl;
            F  |= (u64)f << cl;
        }
        u64* d = NT + (size_t)(cat * 8 + cw) * 5;
        d[0] = p0; d[1] = p1; d[2] = p2; d[3] = p3; d[4] = F;
    }
}

// K0: pack sign(x) bits, word-major xbits[cw][b*HW+p].  Pure streaming, no LDS,
// no barriers; each wave-instruction reads 1KB contiguous; 16 loads in flight.
// grid (784,4) x 256; thread = (b,cw, 4 consecutive positions), cg = 16-ch slice
__global__ __launch_bounds__(256) void xpack_kernel(
    const float* __restrict__ x, u64* __restrict__ xbits) {
    const int tau = blockIdx.x * 256 + threadIdx.x;   // 0..200703
    const int cg  = blockIdx.y;                       // 0..3
    const int pg  = tau % 784;
    const int t2  = tau / 784;                        // b*8+cw
    const int cw  = t2 & 7, b = t2 >> 3;
    const int p0  = pg * 4;

    const float* bp = x + ((size_t)b * CC + cw * 64 + cg * 16) * HW + p0;
    u32 a0 = 0, a1 = 0, a2 = 0, a3 = 0;
    #pragma unroll
    for (int cl = 0; cl < 16; ++cl) {
        float4 v = *(const float4*)(bp + (size_t)cl * HW);
        a0 |= (__float_as_uint(v.x) >> 31) << cl;
        a1 |= (__float_as_uint(v.y) >> 31) << cl;
        a2 |= (__float_as_uint(v.z) >> 31) << cl;
        a3 |= (__float_as_uint(v.w) >> 31) << cl;
    }
    const size_t w = (size_t)cw * NPOS + (size_t)b * HW + p0;
    u16* sp = (u16*)xbits;                            // bit = 1 <=> x >= 0
    sp[(w + 0) * 4 + cg] = (u16)(~a0);
    sp[(w + 1) * 4 + cg] = (u16)(~a1);
    sp[(w + 2) * 4 + cg] = (u16)(~a2);
    sp[(w + 3) * 4 + cg] = (u16)(~a3);
}

__device__ __forceinline__ void fa(u64 a, u64 b, u64 c, u64& s, u64& cy) {
    u64 ab = a ^ b;
    s  = ab ^ c;
    cy = (ab & c) | (a & b);
}

// K1: depthwise 3x3 + BN1 + sign, bit-domain, reading xbits from global (L2/L3-hot).
// grid (392, cw=8) x 256; thread = one output u64 word at position p
__global__ __launch_bounds__(256) void dwbits_kernel(
    const u64* __restrict__ xbits, const u64* __restrict__ wn,
    const u64* __restrict__ NT, u64* __restrict__ s1) {
    const int cw = blockIdx.y;
    const size_t p = (size_t)blockIdx.x * 256 + threadIdx.x;   // 0..100351
    const int b   = (int)(p / HW);
    const int idx = (int)(p - (size_t)b * HW);
    const int r   = idx / WW;
    const int c   = idx - r * WW;

    const u64* xp = xbits + (size_t)cw * NPOS + (size_t)b * HW;
    const int rm = (r == 0)  ? 0  : r - 1;
    const int rp = (r == 55) ? 55 : r + 1;
    const int cm = (c == 0)  ? 0  : c - 1;
    const int cp = (c == 55) ? 55 : c + 1;

    u64 t0 = xp[rm * WW + cm], t1 = xp[rm * WW + c], t2 = xp[rm * WW + cp];
    u64 m0 = xp[r  * WW + cm], m1 = xp[r  * WW + c], m2 = xp[r  * WW + cp];
    u64 b0 = xp[rp * WW + cm], b1 = xp[rp * WW + c], b2 = xp[rp * WW + cp];

    const u64 w00 = wn[0*8+cw], w01 = wn[1*8+cw], w02 = wn[2*8+cw];
    const u64 w10 = wn[3*8+cw], w11 = wn[4*8+cw], w12 = wn[5*8+cw];
    const u64 w20 = wn[6*8+cw], w21 = wn[7*8+cw], w22 = wn[8*8+cw];

    const u64 mt = (r > 0)  ? ~0ull : 0ull;
    const u64 mb = (r < 55) ? ~0ull : 0ull;
    const u64 ml = (c > 0)  ? ~0ull : 0ull;
    const u64 mr = (c < 55) ? ~0ull : 0ull;

    u64 e0 = (t0 ^ w00) & mt & ml;
    u64 e1 = (t1 ^ w01) & mt;
    u64 e2 = (t2 ^ w02) & mt & mr;
    u64 e3 = (m0 ^ w10) & ml;
    u64 e4 = (m1 ^ w11);
    u64 e5 = (m2 ^ w12) & mr;
    u64 e6 = (b0 ^ w20) & mb & ml;
    u64 e7 = (b1 ^ w21) & mb;
    u64 e8 = (b2 ^ w22) & mb & mr;

    u64 sa, ca, sb, cb, sc, cc, E0, cd, se, ce;
    fa(e0, e1, e2, sa, ca);
    fa(e3, e4, e5, sb, cb);
    fa(e6, e7, e8, sc, cc);
    fa(sa, sb, sc, E0, cd);
    fa(ca, cb, cc, se, ce);
    u64 E1 = se ^ cd, cf = se & cd;
    u64 E2 = ce ^ cf, E3 = ce & cf;

    const int rowe = (r == 0) | (r == 55);
    const int cole = (c == 0) | (c == 55);
    const u64* NTp = NT + (size_t)(rowe + cole) * 40 + (size_t)cw * 5;
    u64 n0 = NTp[0], n1 = NTp[1], n2 = NTp[2], n3 = NTp[3], Fv = NTp[4];

    // carry-out of E + ~T* + 1  ->  (E >= T*)
    u64 cr = E0 | n0;
    cr = (E1 & n1) | (cr & (E1 | n1));
    cr = (E2 & n2) | (cr & (E2 | n2));
    cr = (E3 & n3) | (cr & (E3 | n3));

    s1[(size_t)cw * NPOS + p] = cr ^ Fv;
}

// K2: 1x1 binary conv via XNOR-popcount + BN2 (no LDS; weights via scalar cache)
__global__ __launch_bounds__(256) void pw_kernel(
    const u64* __restrict__ s1, const u64* __restrict__ wbits,
    const float* __restrict__ bn2inv, const float* __restrict__ bn2beta,
    float* __restrict__ out) {
    const int tid = threadIdx.x;
    const int o0  = blockIdx.y * 128;

    const size_t p   = (size_t)blockIdx.x * 256 + tid;
    const int    b   = (int)(p / HW);
    const int    idx = (int)(p - (size_t)b * HW);

    u64 r0 = s1[0u * NPOS + p], r1 = s1[1u * NPOS + p];
    u64 r2 = s1[2u * NPOS + p], r3 = s1[3u * NPOS + p];
    u64 r4 = s1[4u * NPOS + p], r5 = s1[5u * NPOS + p];
    u64 r6 = s1[6u * NPOS + p], r7 = s1[7u * NPOS + p];

    const u64*   wp  = wbits + (size_t)o0 * 8;     // wave-uniform -> s_load
    const float* ivp = bn2inv + o0;
    const float* btp = bn2beta + o0;
    float* outp = out + ((size_t)b * COO + o0) * HW + idx;

    #pragma unroll 4
    for (int ol = 0; ol < 128; ++ol) {
        const u64* w8 = wp + ol * 8;
        int d = __popcll(r0 ^ w8[0]) + __popcll(r1 ^ w8[1])
              + __popcll(r2 ^ w8[2]) + __popcll(r3 ^ w8[3])
              + __popcll(r4 ^ w8[4]) + __popcll(r5 ^ w8[5])
              + __popcll(r6 ^ w8[6]) + __popcll(r7 ^ w8[7]);
        float res = (float)(CC - 2 * d);
        outp[(size_t)ol * HW] = fmaf(res, ivp[ol], btp[ol]);
    }
}

extern "C" void kernel_launch(void* const* d_in, const int* in_sizes, int n_in,
                              void* d_out, int out_size, void* d_ws, size_t ws_size,
                              hipStream_t stream) {
    const float* x    = (const float*)d_in[0];
    const float* w_dw = (const float*)d_in[1];
    const float* w_pw = (const float*)d_in[2];
    const float* g1   = (const float*)d_in[3];
    const float* b1   = (const float*)d_in[4];
    const float* m1   = (const float*)d_in[5];
    const float* v1   = (const float*)d_in[6];
    const float* g2   = (const float*)d_in[7];
    const float* b2   = (const float*)d_in[8];
    const float* m2   = (const float*)d_in[9];
    const float* v2   = (const float*)d_in[10];

    char* ws = (char*)d_ws;
    u64*   s1      = (u64*)(ws + OFF_S1);
    u64*   wbits   = (u64*)(ws + OFF_WBITS);
    u64*   wn      = (u64*)(ws + OFF_WN);
    u64*   NTarr   = (u64*)(ws + OFF_NT);
    float* bn2inv  = (float*)(ws + OFF_BN2INV);
    float* bn2beta = (float*)(ws + OFF_BN2BETA);
    u64*   xbits   = (u64*)d_out;        // scratch inside d_out; pw overwrites later

    setup_kernel<<<16, 256, 0, stream>>>(w_dw, w_pw, g1, b1, m1, v1, g2, b2, m2, v2,
                                         wbits, wn, NTarr, bn2inv, bn2beta);

    dim3 g0(784, 4);
    xpack_kernel<<<g0, 256, 0, stream>>>(x, xbits);

    dim3 g1d(392, 8);
    dwbits_kernel<<<g1d, 256, 0, stream>>>(xbits, wn, NTarr, s1);

    dim3 g2d(392, 4);
    pw_kernel<<<g2d, 256, 0, stream>>>(s1, wbits, bn2inv, bn2beta, (float*)d_out);
}